// Round 1
// baseline (746.635 us; speedup 1.0000x reference)
//
#include <hip/hip_runtime.h>

#define K_DIM 4096
#define N_DIM 4096

typedef __bf16 bf16x8 __attribute__((ext_vector_type(8)));
typedef float floatx4 __attribute__((ext_vector_type(4)));

__device__ __forceinline__ unsigned short f32_to_bf16(float f) {
    unsigned int u = __float_as_uint(f);
    u += 0x7fffu + ((u >> 16) & 1u);   // round-to-nearest-even
    return (unsigned short)(u >> 16);
}

// ---------------- kernel 1: sum of |W| ----------------
__global__ void reduce_abs(const float4* __restrict__ W, double* __restrict__ out, int n4) {
    int tid = blockIdx.x * blockDim.x + threadIdx.x;
    int stride = gridDim.x * blockDim.x;
    float s = 0.f;
    for (int i = tid; i < n4; i += stride) {
        float4 v = W[i];
        s += fabsf(v.x) + fabsf(v.y) + fabsf(v.z) + fabsf(v.w);
    }
    double d = (double)s;
#pragma unroll
    for (int o = 32; o > 0; o >>= 1) d += __shfl_down(d, o, 64);
    if ((threadIdx.x & 63) == 0) atomicAdd(out, d);
}

// ---------------- kernel 2: quantize W -> bf16 integers ----------------
__global__ void quant_w(const float4* __restrict__ W, const double* __restrict__ sum,
                        ushort4* __restrict__ Wq, int n4, double inv_cnt) {
    float scale = (float)(*sum * inv_cnt);
    float d = scale + 1e-5f;
    int tid = blockIdx.x * blockDim.x + threadIdx.x;
    int stride = gridDim.x * blockDim.x;
    for (int i = tid; i < n4; i += stride) {
        float4 v = W[i];
        ushort4 q;
        q.x = f32_to_bf16(rintf(v.x / d));   // IEEE divide + RNE round == numpy
        q.y = f32_to_bf16(rintf(v.y / d));
        q.z = f32_to_bf16(rintf(v.z / d));
        q.w = f32_to_bf16(rintf(v.w / d));
        Wq[i] = q;
    }
}

// ---------------- kernel 3: x fp32 -> bf16 ----------------
__global__ void conv_x(const float4* __restrict__ X, ushort4* __restrict__ Xb, int n4) {
    int tid = blockIdx.x * blockDim.x + threadIdx.x;
    int stride = gridDim.x * blockDim.x;
    for (int i = tid; i < n4; i += stride) {
        float4 v = X[i];
        ushort4 q;
        q.x = f32_to_bf16(v.x);
        q.y = f32_to_bf16(v.y);
        q.z = f32_to_bf16(v.z);
        q.w = f32_to_bf16(v.w);
        Xb[i] = q;
    }
}

// ---------------- kernel 4: C[m,n] = scale * sum_k A[m,k]*B[n,k] ----------------
// m97-ladder structure: 128x128 tile, BK=32, 4 waves, global_load_lds width=16.
__global__ __launch_bounds__(256) void gemm_bt(
    const unsigned short* __restrict__ A, const unsigned short* __restrict__ B,
    float* __restrict__ C, const double* __restrict__ sum, double inv_cnt) {
    constexpr int BK = 32;
    __shared__ unsigned short As[128 * BK];
    __shared__ unsigned short Bs[128 * BK];

    const int tid  = threadIdx.x;
    const int wave = tid >> 6;
    const int lane = tid & 63;
    const size_t m0 = (size_t)blockIdx.y * 128;
    const size_t n0 = (size_t)blockIdx.x * 128;

    // staging: wave-issue covers 16 rows (64B each); lane -> row lane>>2, 16B chunk lane&3
    const int srow  = lane >> 2;
    const int skoff = (lane & 3) * 8;
    const int r0a = wave * 16;        // issue 0: rows 0..63 across waves
    const int r0b = 64 + wave * 16;   // issue 1: rows 64..127

    const unsigned short* pa0 = A + (m0 + r0a + srow) * K_DIM + skoff;
    const unsigned short* pa1 = A + (m0 + r0b + srow) * K_DIM + skoff;
    const unsigned short* pb0 = B + (n0 + r0a + srow) * K_DIM + skoff;
    const unsigned short* pb1 = B + (n0 + r0b + srow) * K_DIM + skoff;

    floatx4 acc[4][4] = {};
    const int fm = lane & 15;
    const int fk = (lane >> 4) * 8;
    const int wm = (wave & 1) * 64;
    const int wn = (wave >> 1) * 64;

    for (int kt = 0; kt < K_DIM; kt += BK) {
        __builtin_amdgcn_global_load_lds(
            (const __attribute__((address_space(1))) void*)(pa0 + kt),
            (__attribute__((address_space(3))) void*)&As[r0a * BK], 16, 0, 0);
        __builtin_amdgcn_global_load_lds(
            (const __attribute__((address_space(1))) void*)(pa1 + kt),
            (__attribute__((address_space(3))) void*)&As[r0b * BK], 16, 0, 0);
        __builtin_amdgcn_global_load_lds(
            (const __attribute__((address_space(1))) void*)(pb0 + kt),
            (__attribute__((address_space(3))) void*)&Bs[r0a * BK], 16, 0, 0);
        __builtin_amdgcn_global_load_lds(
            (const __attribute__((address_space(1))) void*)(pb1 + kt),
            (__attribute__((address_space(3))) void*)&Bs[r0b * BK], 16, 0, 0);
        __syncthreads();

        bf16x8 a[4], b[4];
#pragma unroll
        for (int t = 0; t < 4; ++t) {
            a[t] = *(const bf16x8*)&As[(wm + t * 16 + fm) * BK + fk];
            b[t] = *(const bf16x8*)&Bs[(wn + t * 16 + fm) * BK + fk];
        }
#pragma unroll
        for (int ti = 0; ti < 4; ++ti)
#pragma unroll
            for (int tj = 0; tj < 4; ++tj)
                acc[ti][tj] = __builtin_amdgcn_mfma_f32_16x16x32_bf16(
                    a[ti], b[tj], acc[ti][tj], 0, 0, 0);
        __syncthreads();
    }

    float scale = (float)(*sum * inv_cnt);
    const int rbase = (lane >> 4) * 4;
#pragma unroll
    for (int ti = 0; ti < 4; ++ti) {
#pragma unroll
        for (int tj = 0; tj < 4; ++tj) {
            size_t row = m0 + wm + ti * 16 + rbase;
            size_t col = n0 + wn + tj * 16 + fm;
            float* cp = C + row * N_DIM + col;
#pragma unroll
            for (int r = 0; r < 4; ++r)
                cp[(size_t)r * N_DIM] = acc[ti][tj][r] * scale;
        }
    }
}

extern "C" void kernel_launch(void* const* d_in, const int* in_sizes, int n_in,
                              void* d_out, int out_size, void* d_ws, size_t ws_size,
                              hipStream_t stream) {
    const float* x = (const float*)d_in[0];
    const float* W = (const float*)d_in[1];
    float* y = (float*)d_out;

    const int nW = in_sizes[1];            // 4096*4096
    const int M  = in_sizes[0] / K_DIM;    // 8192

    double* d_sum = (double*)d_ws;
    unsigned short* xb = (unsigned short*)((char*)d_ws + 16);
    unsigned short* wq = xb + (size_t)M * K_DIM;
    const double inv_cnt = 1.0 / (double)nW;

    hipMemsetAsync(d_ws, 0, 8, stream);
    reduce_abs<<<1024, 256, 0, stream>>>((const float4*)W, d_sum, nW / 4);
    quant_w<<<2048, 256, 0, stream>>>((const float4*)W, d_sum, (ushort4*)wq, nW / 4, inv_cnt);
    conv_x<<<4096, 256, 0, stream>>>((const float4*)x, (ushort4*)xb, in_sizes[0] / 4);

    dim3 grid(N_DIM / 128, M / 128);
    gemm_bt<<<grid, 256, 0, stream>>>(xb, wq, y, d_sum, inv_cnt);
}

// Round 2
// 731.775 us; speedup vs baseline: 1.0203x; 1.0203x over previous
//
#include <hip/hip_runtime.h>

#define K_DIM 4096
#define N_DIM 4096

typedef __bf16 bf16x8 __attribute__((ext_vector_type(8)));
typedef float floatx4 __attribute__((ext_vector_type(4)));

__device__ __forceinline__ unsigned short f32_to_bf16(float f) {
    unsigned int u = __float_as_uint(f);
    u += 0x7fffu + ((u >> 16) & 1u);   // round-to-nearest-even
    return (unsigned short)(u >> 16);
}

// ---------------- kernel 1a: per-block partial sums of |W| ----------------
__global__ void reduce_abs_p1(const float4* __restrict__ W, double* __restrict__ partials, int n4) {
    int tid = blockIdx.x * blockDim.x + threadIdx.x;
    int stride = gridDim.x * blockDim.x;
    float s = 0.f;
    for (int i = tid; i < n4; i += stride) {
        float4 v = W[i];
        s += fabsf(v.x) + fabsf(v.y) + fabsf(v.z) + fabsf(v.w);
    }
    double d = (double)s;
#pragma unroll
    for (int o = 32; o > 0; o >>= 1) d += __shfl_down(d, o, 64);
    __shared__ double lds[4];
    if ((threadIdx.x & 63) == 0) lds[threadIdx.x >> 6] = d;
    __syncthreads();
    if (threadIdx.x == 0)
        partials[blockIdx.x] = lds[0] + lds[1] + lds[2] + lds[3];
}

// ---------------- kernel 1b: final reduce of 1024 partials ----------------
__global__ void reduce_abs_p2(const double* __restrict__ partials, double* __restrict__ out) {
    double d = 0.0;
#pragma unroll
    for (int i = 0; i < 4; ++i) d += partials[threadIdx.x + i * 256];
#pragma unroll
    for (int o = 32; o > 0; o >>= 1) d += __shfl_down(d, o, 64);
    __shared__ double lds[4];
    if ((threadIdx.x & 63) == 0) lds[threadIdx.x >> 6] = d;
    __syncthreads();
    if (threadIdx.x == 0) *out = lds[0] + lds[1] + lds[2] + lds[3];
}

// ---------------- kernel 2: quantize W -> bf16 integers ----------------
__global__ void quant_w(const float4* __restrict__ W, const double* __restrict__ sum,
                        ushort4* __restrict__ Wq, int n4, double inv_cnt) {
    float scale = (float)(*sum * inv_cnt);
    float d = scale + 1e-5f;
    int tid = blockIdx.x * blockDim.x + threadIdx.x;
    int stride = gridDim.x * blockDim.x;
    for (int i = tid; i < n4; i += stride) {
        float4 v = W[i];
        ushort4 q;
        q.x = f32_to_bf16(rintf(v.x / d));
        q.y = f32_to_bf16(rintf(v.y / d));
        q.z = f32_to_bf16(rintf(v.z / d));
        q.w = f32_to_bf16(rintf(v.w / d));
        Wq[i] = q;
    }
}

// ---------------- kernel 3: x fp32 -> bf16 ----------------
__global__ void conv_x(const float4* __restrict__ X, ushort4* __restrict__ Xb, int n4) {
    int tid = blockIdx.x * blockDim.x + threadIdx.x;
    int stride = gridDim.x * blockDim.x;
    for (int i = tid; i < n4; i += stride) {
        float4 v = X[i];
        ushort4 q;
        q.x = f32_to_bf16(v.x);
        q.y = f32_to_bf16(v.y);
        q.z = f32_to_bf16(v.z);
        q.w = f32_to_bf16(v.w);
        Xb[i] = q;
    }
}

// ---------------- kernel 4: C[m,n] = scale * sum_k A[m,k]*B[n,k] ----------------
// 128x128 tile, BK=64 (32 MFMA per barrier), XOR-swizzled LDS staging (bank-conflict
// free), XCD-aware block remap for L2 locality.
__global__ __launch_bounds__(256) void gemm_bt(
    const unsigned short* __restrict__ A, const unsigned short* __restrict__ B,
    float* __restrict__ C, const double* __restrict__ sum, double inv_cnt) {
    constexpr int BK = 64;                       // shorts; 128 B per row
    __shared__ unsigned short As[128 * BK];      // 16 KB
    __shared__ unsigned short Bs[128 * BK];      // 16 KB

    const int tid  = threadIdx.x;
    const int wave = tid >> 6;
    const int lane = tid & 63;

    // XCD-aware remap: each XCD (blockId%8) owns a compact 16x16 tile region.
    unsigned bl = blockIdx.y * gridDim.x + blockIdx.x;
    unsigned mt, nt;
    if (gridDim.x == 32 && gridDim.y == 64) {
        unsigned xcd = bl & 7, loc = bl >> 3;
        mt = ((xcd >> 1) << 4) | (loc & 15);     // 0..63
        nt = ((xcd & 1) << 4) | (loc >> 4);      // 0..31
    } else {
        mt = blockIdx.y; nt = blockIdx.x;
    }
    const size_t m0 = (size_t)mt * 128;
    const size_t n0 = (size_t)nt * 128;

    // staging: each issue = 8 rows x 128 B. lane -> row lane>>3, fetched 16B-chunk
    // (lane&7)^row  (XOR swizzle: LDS slot s of row r holds global chunk s^(r&7)).
    const int lrow   = lane >> 3;
    const int lchunk = (lane & 7) ^ lrow;
    // wave w stages rows [w*32, w*32+32) of both A and B (4 issues each).
    const int rbase = wave * 32;

    const unsigned short* pA[4];
    const unsigned short* pB[4];
#pragma unroll
    for (int i = 0; i < 4; ++i) {
        pA[i] = A + (m0 + rbase + i * 8 + lrow) * K_DIM + lchunk * 8;
        pB[i] = B + (n0 + rbase + i * 8 + lrow) * K_DIM + lchunk * 8;
    }

    floatx4 acc[4][4] = {};
    const int fm = lane & 15;
    const int q  = lane >> 4;          // 16B chunk within 64B k-half
    const int wm = (wave & 1) * 64;
    const int wn = (wave >> 1) * 64;

    // LDS read offsets (loop-invariant): row m, k-step ks, chunk c = ks*4+q,
    // slot = c ^ (m&7).
    int aoff[4][2], boff[4][2];
#pragma unroll
    for (int t = 0; t < 4; ++t)
#pragma unroll
        for (int ks = 0; ks < 2; ++ks) {
            int ma = wm + t * 16 + fm;
            int mb = wn + t * 16 + fm;
            aoff[t][ks] = ma * BK + (((ks << 2) | q) ^ (ma & 7)) * 8;
            boff[t][ks] = mb * BK + (((ks << 2) | q) ^ (mb & 7)) * 8;
        }

    for (int kt = 0; kt < K_DIM; kt += BK) {
#pragma unroll
        for (int i = 0; i < 4; ++i) {
            __builtin_amdgcn_global_load_lds(
                (const __attribute__((address_space(1))) void*)(pA[i] + kt),
                (__attribute__((address_space(3))) void*)&As[(rbase + i * 8) * BK], 16, 0, 0);
            __builtin_amdgcn_global_load_lds(
                (const __attribute__((address_space(1))) void*)(pB[i] + kt),
                (__attribute__((address_space(3))) void*)&Bs[(rbase + i * 8) * BK], 16, 0, 0);
        }
        __syncthreads();

#pragma unroll
        for (int ks = 0; ks < 2; ++ks) {
            bf16x8 a[4], b[4];
#pragma unroll
            for (int t = 0; t < 4; ++t) {
                a[t] = *(const bf16x8*)&As[aoff[t][ks]];
                b[t] = *(const bf16x8*)&Bs[boff[t][ks]];
            }
#pragma unroll
            for (int ti = 0; ti < 4; ++ti)
#pragma unroll
                for (int tj = 0; tj < 4; ++tj)
                    acc[ti][tj] = __builtin_amdgcn_mfma_f32_16x16x32_bf16(
                        a[ti], b[tj], acc[ti][tj], 0, 0, 0);
        }
        __syncthreads();
    }

    float scale = (float)(*sum * inv_cnt);
    const int rbase_c = (lane >> 4) * 4;
#pragma unroll
    for (int ti = 0; ti < 4; ++ti) {
#pragma unroll
        for (int tj = 0; tj < 4; ++tj) {
            size_t row = m0 + wm + ti * 16 + rbase_c;
            size_t col = n0 + wn + tj * 16 + fm;
            float* cp = C + row * N_DIM + col;
#pragma unroll
            for (int r = 0; r < 4; ++r)
                cp[(size_t)r * N_DIM] = acc[ti][tj][r] * scale;
        }
    }
}

extern "C" void kernel_launch(void* const* d_in, const int* in_sizes, int n_in,
                              void* d_out, int out_size, void* d_ws, size_t ws_size,
                              hipStream_t stream) {
    const float* x = (const float*)d_in[0];
    const float* W = (const float*)d_in[1];
    float* y = (float*)d_out;

    const int nW = in_sizes[1];            // 4096*4096
    const int M  = in_sizes[0] / K_DIM;    // 8192

    double* d_sum = (double*)d_ws;
    double* d_partials = (double*)((char*)d_ws + 16);
    unsigned short* xb = (unsigned short*)((char*)d_ws + 16 + 1024 * sizeof(double));
    unsigned short* wq = xb + (size_t)M * K_DIM;
    const double inv_cnt = 1.0 / (double)nW;

    reduce_abs_p1<<<1024, 256, 0, stream>>>((const float4*)W, d_partials, nW / 4);
    reduce_abs_p2<<<1, 256, 0, stream>>>(d_partials, d_sum);
    quant_w<<<2048, 256, 0, stream>>>((const float4*)W, d_sum, (ushort4*)wq, nW / 4, inv_cnt);
    conv_x<<<4096, 256, 0, stream>>>((const float4*)x, (ushort4*)xb, in_sizes[0] / 4);

    dim3 grid(N_DIM / 128, M / 128);
    gemm_bt<<<grid, 256, 0, stream>>>(xb, wq, y, d_sum, inv_cnt);
}

// Round 3
// 719.544 us; speedup vs baseline: 1.0377x; 1.0170x over previous
//
#include <hip/hip_runtime.h>

#define K_DIM 4096
#define N_DIM 4096

typedef __bf16 bf16x8 __attribute__((ext_vector_type(8)));
typedef float floatx4 __attribute__((ext_vector_type(4)));

__device__ __forceinline__ unsigned short f32_to_bf16(float f) {
    unsigned int u = __float_as_uint(f);
    u += 0x7fffu + ((u >> 16) & 1u);   // round-to-nearest-even
    return (unsigned short)(u >> 16);
}

// ---------------- kernel 1a: per-block partial sums of |W| ----------------
__global__ void reduce_abs_p1(const float4* __restrict__ W, double* __restrict__ partials, int n4) {
    int tid = blockIdx.x * blockDim.x + threadIdx.x;
    int stride = gridDim.x * blockDim.x;
    float s = 0.f;
    for (int i = tid; i < n4; i += stride) {
        float4 v = W[i];
        s += fabsf(v.x) + fabsf(v.y) + fabsf(v.z) + fabsf(v.w);
    }
    double d = (double)s;
#pragma unroll
    for (int o = 32; o > 0; o >>= 1) d += __shfl_down(d, o, 64);
    __shared__ double lds[4];
    if ((threadIdx.x & 63) == 0) lds[threadIdx.x >> 6] = d;
    __syncthreads();
    if (threadIdx.x == 0)
        partials[blockIdx.x] = lds[0] + lds[1] + lds[2] + lds[3];
}

// ---------------- kernel 1b: final reduce of 1024 partials ----------------
__global__ void reduce_abs_p2(const double* __restrict__ partials, double* __restrict__ out) {
    double d = 0.0;
#pragma unroll
    for (int i = 0; i < 4; ++i) d += partials[threadIdx.x + i * 256];
#pragma unroll
    for (int o = 32; o > 0; o >>= 1) d += __shfl_down(d, o, 64);
    __shared__ double lds[4];
    if ((threadIdx.x & 63) == 0) lds[threadIdx.x >> 6] = d;
    __syncthreads();
    if (threadIdx.x == 0) *out = lds[0] + lds[1] + lds[2] + lds[3];
}

// ---------------- kernel 2: fused W-quantize + x-convert ----------------
__global__ void prep(const float4* __restrict__ W, const float4* __restrict__ X,
                     const double* __restrict__ sum,
                     ushort4* __restrict__ Wq, ushort4* __restrict__ Xb,
                     int nW4, int nX4, double inv_cnt) {
    float scale = (float)(*sum * inv_cnt);
    float d = scale + 1e-5f;
    int tid = blockIdx.x * blockDim.x + threadIdx.x;
    int stride = gridDim.x * blockDim.x;
    for (int i = tid; i < nW4; i += stride) {
        float4 v = W[i];
        ushort4 q;
        q.x = f32_to_bf16(rintf(v.x / d));   // IEEE divide + RNE == numpy round-half-even
        q.y = f32_to_bf16(rintf(v.y / d));
        q.z = f32_to_bf16(rintf(v.z / d));
        q.w = f32_to_bf16(rintf(v.w / d));
        Wq[i] = q;
    }
    for (int i = tid; i < nX4; i += stride) {
        float4 v = X[i];
        ushort4 q;
        q.x = f32_to_bf16(v.x);
        q.y = f32_to_bf16(v.y);
        q.z = f32_to_bf16(v.z);
        q.w = f32_to_bf16(v.w);
        Xb[i] = q;
    }
}

// ---------------- kernel 3: C[m,n] = scale * sum_k A[m,k]*B[n,k] ----------------
// 128x128 tile, BK=32, DOUBLE-BUFFERED LDS (one barrier per tile: next tile's
// global_load_lds issued before compute, so the barrier's vmcnt(0) drain is
// covered by ~600 cyc of MFMA). XOR swizzle f(r)=(r+(r>>1))&3 keeps LDS reads
// conflict-free at 64 B row pitch.
__global__ __launch_bounds__(256) void gemm_bt(
    const unsigned short* __restrict__ A, const unsigned short* __restrict__ B,
    float* __restrict__ C, const double* __restrict__ sum, double inv_cnt) {
    constexpr int BK = 32;                         // shorts; 64 B per row
    __shared__ unsigned short As[2][128 * BK];     // 2 x 8 KB
    __shared__ unsigned short Bs[2][128 * BK];     // 2 x 8 KB

    const int tid  = threadIdx.x;
    const int wave = tid >> 6;
    const int lane = tid & 63;
    const size_t m0 = (size_t)blockIdx.y * 128;
    const size_t n0 = (size_t)blockIdx.x * 128;

    // staging: one issue = 16 rows x 64 B. lane -> row lane>>2, LDS slot lane&3,
    // fetched global 16B-chunk = (lane&3) ^ f(row),  f(r) = (r + r/2) & 3.
    const int srow   = lane >> 2;
    const int fsw    = (srow + (srow >> 1)) & 3;
    const int schunk = (lane & 3) ^ fsw;
    const int r0a = wave * 16;        // rows 0..63 across waves
    const int r0b = 64 + wave * 16;   // rows 64..127

    const unsigned short* pa0 = A + (m0 + r0a + srow) * K_DIM + schunk * 8;
    const unsigned short* pa1 = A + (m0 + r0b + srow) * K_DIM + schunk * 8;
    const unsigned short* pb0 = B + (n0 + r0a + srow) * K_DIM + schunk * 8;
    const unsigned short* pb1 = B + (n0 + r0b + srow) * K_DIM + schunk * 8;

    floatx4 acc[4][4] = {};
    const int fm = lane & 15;
    const int q  = lane >> 4;          // k-chunk (8 shorts) within BK=32
    const int wm = (wave & 1) * 64;
    const int wn = (wave >> 1) * 64;

    // LDS fragment offsets (loop-invariant): row m reads slot q ^ f(m).
    int aoff[4], boff[4];
#pragma unroll
    for (int t = 0; t < 4; ++t) {
        int ma = wm + t * 16 + fm;
        int mb = wn + t * 16 + fm;
        aoff[t] = ma * BK + ((q ^ ((ma + (ma >> 1)) & 3)) * 8);
        boff[t] = mb * BK + ((q ^ ((mb + (mb >> 1)) & 3)) * 8);
    }

#define STAGE(buf, kt)                                                                   \
    do {                                                                                 \
        __builtin_amdgcn_global_load_lds(                                                \
            (const __attribute__((address_space(1))) void*)(pa0 + (kt)),                 \
            (__attribute__((address_space(3))) void*)&As[buf][r0a * BK], 16, 0, 0);      \
        __builtin_amdgcn_global_load_lds(                                                \
            (const __attribute__((address_space(1))) void*)(pa1 + (kt)),                 \
            (__attribute__((address_space(3))) void*)&As[buf][r0b * BK], 16, 0, 0);      \
        __builtin_amdgcn_global_load_lds(                                                \
            (const __attribute__((address_space(1))) void*)(pb0 + (kt)),                 \
            (__attribute__((address_space(3))) void*)&Bs[buf][r0a * BK], 16, 0, 0);      \
        __builtin_amdgcn_global_load_lds(                                                \
            (const __attribute__((address_space(1))) void*)(pb1 + (kt)),                 \
            (__attribute__((address_space(3))) void*)&Bs[buf][r0b * BK], 16, 0, 0);      \
    } while (0)

#define COMPUTE(buf)                                                                     \
    do {                                                                                 \
        bf16x8 a[4], b[4];                                                               \
        _Pragma("unroll")                                                                \
        for (int t = 0; t < 4; ++t) {                                                    \
            a[t] = *(const bf16x8*)&As[buf][aoff[t]];                                    \
            b[t] = *(const bf16x8*)&Bs[buf][boff[t]];                                    \
        }                                                                                \
        _Pragma("unroll")                                                                \
        for (int ti = 0; ti < 4; ++ti)                                                   \
            _Pragma("unroll")                                                            \
            for (int tj = 0; tj < 4; ++tj)                                               \
                acc[ti][tj] = __builtin_amdgcn_mfma_f32_16x16x32_bf16(                   \
                    a[ti], b[tj], acc[ti][tj], 0, 0, 0);                                 \
    } while (0)

    STAGE(0, 0);
    __syncthreads();
    for (int kt = 0; kt < K_DIM; kt += 2 * BK) {
        STAGE(1, kt + BK);                 // in flight during compute(0)
        COMPUTE(0);
        __syncthreads();                   // drains buf1 loads + buf0 reads
        if (kt + 2 * BK < K_DIM)
            STAGE(0, kt + 2 * BK);         // in flight during compute(1)
        COMPUTE(1);
        __syncthreads();
    }

    float scale = (float)(*sum * inv_cnt);
    const int rbase_c = (lane >> 4) * 4;
#pragma unroll
    for (int ti = 0; ti < 4; ++ti) {
#pragma unroll
        for (int tj = 0; tj < 4; ++tj) {
            size_t row = m0 + wm + ti * 16 + rbase_c;
            size_t col = n0 + wn + tj * 16 + fm;
            float* cp = C + row * N_DIM + col;
#pragma unroll
            for (int r = 0; r < 4; ++r)
                cp[(size_t)r * N_DIM] = acc[ti][tj][r] * scale;
        }
    }
#undef STAGE
#undef COMPUTE
}

extern "C" void kernel_launch(void* const* d_in, const int* in_sizes, int n_in,
                              void* d_out, int out_size, void* d_ws, size_t ws_size,
                              hipStream_t stream) {
    const float* x = (const float*)d_in[0];
    const float* W = (const float*)d_in[1];
    float* y = (float*)d_out;

    const int nW = in_sizes[1];            // 4096*4096
    const int M  = in_sizes[0] / K_DIM;    // 8192

    double* d_sum = (double*)d_ws;
    double* d_partials = (double*)((char*)d_ws + 16);
    unsigned short* xb = (unsigned short*)((char*)d_ws + 16 + 1024 * sizeof(double));
    unsigned short* wq = xb + (size_t)M * K_DIM;
    const double inv_cnt = 1.0 / (double)nW;

    reduce_abs_p1<<<1024, 256, 0, stream>>>((const float4*)W, d_partials, nW / 4);
    reduce_abs_p2<<<1, 256, 0, stream>>>(d_partials, d_sum);
    prep<<<2048, 256, 0, stream>>>((const float4*)W, (const float4*)x, d_sum,
                                   (ushort4*)wq, (ushort4*)xb,
                                   nW / 4, in_sizes[0] / 4, inv_cnt);

    dim3 grid(N_DIM / 128, M / 128);
    gemm_bt<<<grid, 256, 0, stream>>>(xb, wq, y, d_sum, inv_cnt);
}